// Round 6
// baseline (99.302 us; speedup 1.0000x reference)
//
#include <hip/hip_runtime.h>
#include <hip/hip_bf16.h>

// Attention cosine-sim + mask + softmax — fused, online-softmax streaming.
// query (16,16,1,128) f32, key (16,16,4096,128) f32, mask (16,4096) i32
// out (16,16,4096) f32
//
// Mask is staged to LDS up front; each 32-lane group's writer lane keeps a
// running (max, sum) online during the key stream, so the post-stream tail is
// one barrier + a 32-way merge + one exp/scale/store pass.

constexpr int Bdim = 16, Hdim = 16, Ldim = 4096, Ddim = 128;
constexpr int NTHREADS = 1024;           // 16 waves
constexpr float EPSF = 1e-8f;
constexpr float NEGF = -1000000000.0f;

// 32-lane-group sum via DPP row ops (VALU pipe, zero DS traffic).
// Valid result in lane 31 of each 32-lane half (lanes 31 and 63 of the wave).
__device__ __forceinline__ float dpp_sum32(float v) {
    v += __int_as_float(__builtin_amdgcn_update_dpp(0, __float_as_int(v), 0x111, 0xf, 0xf, true)); // row_shr:1
    v += __int_as_float(__builtin_amdgcn_update_dpp(0, __float_as_int(v), 0x112, 0xf, 0xf, true)); // row_shr:2
    v += __int_as_float(__builtin_amdgcn_update_dpp(0, __float_as_int(v), 0x114, 0xf, 0xf, true)); // row_shr:4
    v += __int_as_float(__builtin_amdgcn_update_dpp(0, __float_as_int(v), 0x118, 0xf, 0xf, true)); // row_shr:8
    v += __int_as_float(__builtin_amdgcn_update_dpp(0, __float_as_int(v), 0x142, 0xa, 0xf, true)); // row_bcast:15 -> rows 1,3
    return v;
}

__global__ __launch_bounds__(NTHREADS, 8) void attn_cos_softmax(
    const float* __restrict__ q,
    const float* __restrict__ k,
    const int* __restrict__ mask,
    float* __restrict__ out)
{
    const int bh = blockIdx.x;           // 0..255
    const int b  = bh >> 4;              // / Hdim
    const float4* qrow = reinterpret_cast<const float4*>(q + (size_t)bh * Ddim);
    const float4* krow = reinterpret_cast<const float4*>(k + (size_t)bh * Ldim * Ddim);
    const int*    mrow = mask + (size_t)b * Ldim;
    float*        orow = out  + (size_t)bh * Ldim;

    __shared__ float s_scores[Ldim];     // 16 KB
    __shared__ int   s_mask[Ldim];       // 16 KB
    __shared__ float s_m[32];
    __shared__ float s_z[32];

    const int tid  = threadIdx.x;
    const int g    = tid >> 5;           // 32-lane group id, 0..31
    const int lane = tid & 31;
    const bool writer = (lane == 31);    // DPP reduction lands in lane 31 of each group

    // stage mask into LDS (one coalesced int4 per thread)
    reinterpret_cast<int4*>(s_mask)[tid] = reinterpret_cast<const int4*>(mrow)[tid];

    // q fragment (float4 per lane covers the 128-elem row across 32 lanes) + ||q||
    float4 qv = qrow[lane];
    float q2 = qv.x*qv.x + qv.y*qv.y + qv.z*qv.z + qv.w*qv.w;
    q2 = dpp_sum32(q2);                  // valid on writer lane only — that's all we need
    const float qn = sqrtf(q2);

    __syncthreads();                     // mask staged

    // ---- streaming phase with online (m, z) on writer lanes ----
    float m_g = -3.0e9f;                 // below NEG so an all-masked row matches reference
    float z_g = 0.0f;

    constexpr int UNROLL = 8;
    constexpr int ROWS_PER_ITER = 32 * UNROLL;   // 256 rows per block iteration
    #pragma unroll 1
    for (int iter = 0; iter < Ldim / ROWS_PER_ITER; ++iter) {
        const int base = iter * ROWS_PER_ITER + g;
        float4 kv[UNROLL];
        #pragma unroll
        for (int j = 0; j < UNROLL; ++j) {
            kv[j] = krow[(base + j * 32) * (Ddim / 4) + lane];
        }
        #pragma unroll
        for (int j = 0; j < UNROLL; ++j) {
            float dp = kv[j].x*qv.x + kv[j].y*qv.y + kv[j].z*qv.z + kv[j].w*qv.w;
            float k2 = kv[j].x*kv[j].x + kv[j].y*kv[j].y + kv[j].z*kv[j].z + kv[j].w*kv[j].w;
            dp = dpp_sum32(dp);
            k2 = dpp_sum32(k2);
            if (writer) {
                const int row = base + j * 32;
                float denom = fmaxf(qn * sqrtf(k2), EPSF);
                float s = dp / denom;
                s = (s_mask[row] == 0) ? NEGF : s;
                s_scores[row] = s;
                float mn = fmaxf(m_g, s);
                z_g = z_g * __expf(m_g - mn) + __expf(s - mn);
                m_g = mn;
            }
        }
    }
    if (writer) { s_m[g] = m_g; s_z[g] = z_g; }
    __syncthreads();

    // ---- merge 32 partials (redundantly per thread; LDS broadcast reads) ----
    float gmax = s_m[0];
    #pragma unroll
    for (int i = 1; i < 32; ++i) gmax = fmaxf(gmax, s_m[i]);
    float gz = 0.0f;
    #pragma unroll
    for (int i = 0; i < 32; ++i) gz += s_z[i] * __expf(s_m[i] - gmax);
    const float rinv = 1.0f / gz;

    // ---- epilogue: exp, scale, store ----
    #pragma unroll
    for (int i = 0; i < 4; ++i) {
        const int idx = tid + i * NTHREADS;
        orow[idx] = __expf(s_scores[idx] - gmax) * rinv;
    }
}

extern "C" void kernel_launch(void* const* d_in, const int* in_sizes, int n_in,
                              void* d_out, int out_size, void* d_ws, size_t ws_size,
                              hipStream_t stream) {
    const float* q    = (const float*)d_in[0];
    const float* k    = (const float*)d_in[1];
    const int*   mask = (const int*)d_in[2];
    float*       out  = (float*)d_out;

    dim3 grid(Bdim * Hdim);
    dim3 block(NTHREADS);
    attn_cos_softmax<<<grid, block, 0, stream>>>(q, k, mask, out);
}

// Round 8
// 87.278 us; speedup vs baseline: 1.1378x; 1.1378x over previous
//
#include <hip/hip_runtime.h>
#include <hip/hip_bf16.h>

// Attention cosine-sim + mask + softmax — fused (R5 structure) +
// non-temporal key loads (via clang ext_vector_type) + mask pre-staged in LDS.
// query (16,16,1,128) f32, key (16,16,4096,128) f32, mask (16,4096) i32
// out (16,16,4096) f32

constexpr int Bdim = 16, Hdim = 16, Ldim = 4096, Ddim = 128;
constexpr int NTHREADS = 1024;           // 16 waves
constexpr float EPSF = 1e-8f;
constexpr float NEGF = -1000000000.0f;

typedef float floatx4 __attribute__((ext_vector_type(4)));

// 32-lane-group sum via DPP row ops (VALU pipe, zero DS traffic).
// Valid result in lane 31 of each 32-lane half (lanes 31 and 63 of the wave).
__device__ __forceinline__ float dpp_sum32(float v) {
    v += __int_as_float(__builtin_amdgcn_update_dpp(0, __float_as_int(v), 0x111, 0xf, 0xf, true)); // row_shr:1
    v += __int_as_float(__builtin_amdgcn_update_dpp(0, __float_as_int(v), 0x112, 0xf, 0xf, true)); // row_shr:2
    v += __int_as_float(__builtin_amdgcn_update_dpp(0, __float_as_int(v), 0x114, 0xf, 0xf, true)); // row_shr:4
    v += __int_as_float(__builtin_amdgcn_update_dpp(0, __float_as_int(v), 0x118, 0xf, 0xf, true)); // row_shr:8
    v += __int_as_float(__builtin_amdgcn_update_dpp(0, __float_as_int(v), 0x142, 0xa, 0xf, true)); // row_bcast:15 -> rows 1,3
    return v;
}

__global__ __launch_bounds__(NTHREADS, 8) void attn_cos_softmax(
    const float* __restrict__ q,
    const float* __restrict__ k,
    const int* __restrict__ mask,
    float* __restrict__ out)
{
    const int bh = blockIdx.x;           // 0..255
    const int b  = bh >> 4;              // / Hdim
    const floatx4* qrow = reinterpret_cast<const floatx4*>(q + (size_t)bh * Ddim);
    const floatx4* krow = reinterpret_cast<const floatx4*>(k + (size_t)bh * Ldim * Ddim);
    const int*     mrow = mask + (size_t)b * Ldim;
    float*         orow = out  + (size_t)bh * Ldim;

    __shared__ float s_scores[Ldim];     // 16 KB
    __shared__ int   s_mask[Ldim];       // 16 KB
    __shared__ float s_red[16];

    const int tid  = threadIdx.x;
    const int g    = tid >> 5;           // 32-lane group id, 0..31
    const int lane = tid & 31;
    const bool writer = (lane == 31);    // DPP reduction lands in lane 31 of each group

    // stage mask into LDS (one coalesced int4 per thread); the post-stream
    // __syncthreads() orders this for the tail — no extra barrier needed.
    reinterpret_cast<int4*>(s_mask)[tid] = reinterpret_cast<const int4*>(mrow)[tid];

    // q fragment (float4 per lane covers the 128-elem row across 32 lanes) + ||q||
    floatx4 qv = qrow[lane];
    float q2 = qv.x*qv.x + qv.y*qv.y + qv.z*qv.z + qv.w*qv.w;
    q2 = dpp_sum32(q2);                  // valid on writer lane only — that's all we need
    const float qn = sqrtf(q2);

    // ---- score phase: 8 rows batched per 32-lane group, non-temporal reads ----
    constexpr int UNROLL = 8;
    constexpr int ROWS_PER_ITER = 32 * UNROLL;   // 256 rows per block iteration
    #pragma unroll 1
    for (int iter = 0; iter < Ldim / ROWS_PER_ITER; ++iter) {
        const int base = iter * ROWS_PER_ITER + g;
        floatx4 kv[UNROLL];
        #pragma unroll
        for (int j = 0; j < UNROLL; ++j) {
            kv[j] = __builtin_nontemporal_load(&krow[(base + j * 32) * (Ddim / 4) + lane]);
        }
        #pragma unroll
        for (int j = 0; j < UNROLL; ++j) {
            float dp = kv[j].x*qv.x + kv[j].y*qv.y + kv[j].z*qv.z + kv[j].w*qv.w;
            float k2 = kv[j].x*kv[j].x + kv[j].y*kv[j].y + kv[j].z*kv[j].z + kv[j].w*kv[j].w;
            dp = dpp_sum32(dp);
            k2 = dpp_sum32(k2);
            if (writer) {
                float denom = fmaxf(qn * sqrtf(k2), EPSF);
                s_scores[base + j * 32] = dp / denom;
            }
        }
    }
    __syncthreads();

    // ---- softmax over L = 4096 (4 elements per thread, in registers) ----
    float sv[4];
    float lmax = -3.0e9f;   // below NEG so an all-masked row matches reference
    #pragma unroll
    for (int i = 0; i < 4; ++i) {
        const int idx = tid + i * NTHREADS;
        float s = s_scores[idx];
        s = (s_mask[idx] == 0) ? NEGF : s;
        sv[i] = s;
        lmax = fmaxf(lmax, s);
    }
    #pragma unroll
    for (int m = 32; m >= 1; m >>= 1) lmax = fmaxf(lmax, __shfl_xor(lmax, m));
    if ((tid & 63) == 0) s_red[tid >> 6] = lmax;
    __syncthreads();
    float gmax = s_red[0];
    #pragma unroll
    for (int i = 1; i < 16; ++i) gmax = fmaxf(gmax, s_red[i]);
    __syncthreads();

    float lsum = 0.0f;
    #pragma unroll
    for (int i = 0; i < 4; ++i) {
        sv[i] = __expf(sv[i] - gmax);    // reuse sv as exp values
        lsum += sv[i];
    }
    #pragma unroll
    for (int m = 32; m >= 1; m >>= 1) lsum += __shfl_xor(lsum, m);
    if ((tid & 63) == 0) s_red[tid >> 6] = lsum;
    __syncthreads();
    float gsum = 0.0f;
    #pragma unroll
    for (int i = 0; i < 16; ++i) gsum += s_red[i];
    const float rinv = 1.0f / gsum;

    #pragma unroll
    for (int i = 0; i < 4; ++i) {
        orow[tid + i * NTHREADS] = sv[i] * rinv;
    }
}

extern "C" void kernel_launch(void* const* d_in, const int* in_sizes, int n_in,
                              void* d_out, int out_size, void* d_ws, size_t ws_size,
                              hipStream_t stream) {
    const float* q    = (const float*)d_in[0];
    const float* k    = (const float*)d_in[1];
    const int*   mask = (const int*)d_in[2];
    float*       out  = (float*)d_out;

    dim3 grid(Bdim * Hdim);
    dim3 block(NTHREADS);
    attn_cos_softmax<<<grid, block, 0, stream>>>(q, k, mask, out);
}